// Round 9
// baseline (68.609 us; speedup 1.0000x reference)
//
#include <hip/hip_runtime.h>

#define IMG 512
#define NPIX (IMG*IMG)
#define NBLK 256

#define ST_AGENT(p, v) __hip_atomic_store((p), (v), __ATOMIC_RELAXED, __HIP_MEMORY_SCOPE_AGENT)
#define LD_AGENT(p)    __hip_atomic_load((p), __ATOMIC_RELAXED, __HIP_MEMORY_SCOPE_AGENT)

// ---------------------------------------------------------------------------
// Fused v3: one kernel, 256 blocks x 256 threads, all co-resident (<=2/CU).
// R5-R7 stall diagnosis fixed here:
//  (a) part is TRANSPOSED [slot][640 units]; phase-B reads are normal cached
//      float4 (coalesced), correctness via ONE acquire fence per block after
//      the barrier (sc1 stores -> IC; buffer_inv once, not per poll).
//  (b) barrier arrivals spread over 32 counter lines (64B apart).
//  (c) poll: one wave, lane i watches line i, shuffle-sum, s_sleep(8).
// Phase A: 640 gram units (2b x 5dy x 64 strips of 8 rows), 2-3 per block.
// Phase B: every block redundantly: part -> L -> attn -> 3x3 taps in LDS.
// Phase C: out = x + conv3x3(x0;A) + conv3x3(x1;B), 2 quad-pixels/thread.
// ---------------------------------------------------------------------------
__global__ __launch_bounds__(256,2) void fused_kernel(
    const float* __restrict__ x, const float* __restrict__ e,
    const float* __restrict__ w_conv1, const float* __restrict__ w_dw,
    const float* __restrict__ w_ehead, const float* __restrict__ w_proj,
    const float* __restrict__ a1,
    float* __restrict__ part, unsigned int* __restrict__ bar,
    float* __restrict__ out)
{
  const int blk = blockIdx.x;
  const int tid = threadIdx.x;

  __shared__ float red[4][30];
  __shared__ float Lred[2][150];
  __shared__ float we_lds[128][9];
  __shared__ float nk_lds[2][128];
  __shared__ float attn_lds[2][8][16][16];
  __shared__ float M_lds[2][2][128];
  __shared__ float AB_lds[2][2][2][9];   // [b][o][A/B][tap]

  // ----------------------------- Phase A: gram -----------------------------
  for (int u = blk; u < 640; u += NBLK){
    const int strip = u & 63;
    const int dyi = (u >> 6) % 5;
    const int dy  = dyi - 2;
    const int b   = u / 320;
    const int cx  = (tid & 127) << 2;
    const int r0  = (strip << 3) + ((tid >> 7) << 2);    // 4 rows per thread
    const float* x0 = x + (size_t)b*2*NPIX;
    const float* x1 = x0 + NPIX;
    const float* ep = e + (size_t)b*NPIX;

    float acc[6][5];
#pragma unroll
    for (int t=0;t<6;t++)
#pragma unroll
      for (int j=0;j<5;j++) acc[t][j]=0.f;

    const bool okL = (cx >= 4), okR = (cx < 508);

#pragma unroll 2
    for (int s=0;s<4;s++){
      const int r = r0+s;
      const float4 a0 = *(const float4*)(x0 + r*IMG + cx);
      const float4 a1v= *(const float4*)(x1 + r*IMG + cx);
      const float4 aE = *(const float4*)(ep + r*IMG + cx);
      const int rb = r+dy;
      if ((unsigned)rb < (unsigned)IMG){
        const float* p0 = x0 + rb*IMG;
        const float* p1 = x1 + rb*IMG;
        const float* pe = ep + rb*IMG;
        float w0[8], w1[8], wE[8];
        {
          const float4 z = make_float4(0.f,0.f,0.f,0.f);
          float4 L,M,R;
          L = okL ? *(const float4*)(p0+cx-4) : z;
          M = *(const float4*)(p0+cx);
          R = okR ? *(const float4*)(p0+cx+4) : z;
          w0[0]=L.z;w0[1]=L.w;w0[2]=M.x;w0[3]=M.y;w0[4]=M.z;w0[5]=M.w;w0[6]=R.x;w0[7]=R.y;
          L = okL ? *(const float4*)(p1+cx-4) : z;
          M = *(const float4*)(p1+cx);
          R = okR ? *(const float4*)(p1+cx+4) : z;
          w1[0]=L.z;w1[1]=L.w;w1[2]=M.x;w1[3]=M.y;w1[4]=M.z;w1[5]=M.w;w1[6]=R.x;w1[7]=R.y;
          L = okL ? *(const float4*)(pe+cx-4) : z;
          M = *(const float4*)(pe+cx);
          R = okR ? *(const float4*)(pe+cx+4) : z;
          wE[0]=L.z;wE[1]=L.w;wE[2]=M.x;wE[3]=M.y;wE[4]=M.z;wE[5]=M.w;wE[6]=R.x;wE[7]=R.y;
        }
#pragma unroll
        for (int j=0;j<5;j++){
          acc[0][j] += a0.x*w0[j] + a0.y*w0[j+1] + a0.z*w0[j+2] + a0.w*w0[j+3];
          acc[1][j] += a0.x*w1[j] + a0.y*w1[j+1] + a0.z*w1[j+2] + a0.w*w1[j+3];
          acc[2][j] += a1v.x*w1[j] + a1v.y*w1[j+1] + a1v.z*w1[j+2] + a1v.w*w1[j+3];
          acc[3][j] += a0.x*wE[j] + a0.y*wE[j+1] + a0.z*wE[j+2] + a0.w*wE[j+3];
          acc[4][j] += a1v.x*wE[j] + a1v.y*wE[j+1] + a1v.z*wE[j+2] + a1v.w*wE[j+3];
          acc[5][j] += aE.x*wE[j] + aE.y*wE[j+1] + aE.z*wE[j+2] + aE.w*wE[j+3];
        }
      }
    }

    const int wv   = tid >> 6;
    const int lane = tid & 63;
#pragma unroll
    for (int t=0;t<6;t++)
#pragma unroll
      for (int j=0;j<5;j++){
        float v = acc[t][j];
        for (int off=32; off; off>>=1) v += __shfl_down(v, off);
        if (lane==0) red[wv][t*5+j] = v;
      }
    __syncthreads();
    if (tid < 30)
      ST_AGENT(&part[tid*640 + u],                       // transposed [slot][unit]
               red[0][tid]+red[1][tid]+red[2][tid]+red[3][tid]);
    __syncthreads();   // protect red[] before next unit's reduce
  }

  // ------------------------ software grid barrier --------------------------
  // __syncthreads drained vmcnt: this block's sc1 part stores are at the IC.
  if (tid == 0)
    __hip_atomic_fetch_add(&bar[(blk & 31) << 4], 1u,
                           __ATOMIC_RELAXED, __HIP_MEMORY_SCOPE_AGENT);
  if (tid < 32){
    unsigned total;
    do {
      unsigned v = LD_AGENT(&bar[tid << 4]);
      v += __shfl_down(v, 16, 32);
      v += __shfl_down(v,  8, 32);
      v += __shfl_down(v,  4, 32);
      v += __shfl_down(v,  2, 32);
      v += __shfl_down(v,  1, 32);
      total = __shfl(v, 0, 32);
      if (total < NBLK) __builtin_amdgcn_s_sleep(8);
    } while (total < NBLK);
  }
  __syncthreads();
  // One inv per wave: drop any stale L1/L2 copies of part, then read cached.
  __builtin_amdgcn_fence(__ATOMIC_ACQUIRE, "agent");

  // ------------------- Phase B: attn (redundant per block) -----------------
  {
    for (int i=tid; i<300; i+=256){
      const int bb=i/150, li=i%150;
      const int t=li/25, lag=li%25, dyi=lag/5, dxi=lag%5;
      const float4* p = (const float4*)(part + (t*5+dxi)*640 + bb*320 + dyi*64);
      float4 s4 = make_float4(0.f,0.f,0.f,0.f);
#pragma unroll
      for (int j=0;j<16;j++){
        const float4 v = p[j];
        s4.x += v.x; s4.y += v.y; s4.z += v.z; s4.w += v.w;
      }
      Lred[bb][li] = (s4.x+s4.y)+(s4.z+s4.w);
    }
    if (tid<128){
#pragma unroll
      for (int t=0;t<9;t++) we_lds[tid][t]=w_ehead[tid*9+t];
    }
    __syncthreads();

    const int b=tid>>7, h=(tid>>4)&7, c=tid&15;
    const int C=h*16+c;
    const float* Lb  = Lred[b];
    const float* L00=Lb, *L01=Lb+25, *L11=Lb+50, *L0e=Lb+75, *L1e=Lb+100, *Lee=Lb+125;

    float u[9], v[9];
    {
      const float wa=w_conv1[C*2+0], wb=w_conv1[C*2+1];
#pragma unroll
      for (int t=0;t<9;t++){ const float wd=w_dw[C*9+t]; u[t]=wd*wa; v[t]=wd*wb; }
    }
    float nq2=0.f, nk2=0.f;
#pragma unroll
    for (int t=0;t<9;t++){
      const int ty=t/3, tx=t%3;
#pragma unroll
      for (int t2=0;t2<9;t2++){
        const int dy=t2/3-ty, dx=t2%3-tx;
        const int di=( dy+2)*5+( dx+2);
        const int dj=(-dy+2)*5+(-dx+2);
        nq2 += u[t]*u[t2]*L00[di] + u[t]*v[t2]*L01[di] + v[t]*u[t2]*L01[dj] + v[t]*v[t2]*L11[di];
        nk2 += we_lds[C][t]*we_lds[C][t2]*Lee[di];
      }
    }
    nk_lds[b][C]=sqrtf(nk2);
    float P[9];
#pragma unroll
    for (int t2=0;t2<9;t2++){
      float s=0.f;
      const int t2y=t2/3, t2x=t2%3;
#pragma unroll
      for (int t=0;t<9;t++){
        const int di=(t2y-t/3+2)*5+(t2x-t%3+2);
        s += u[t]*L0e[di] + v[t]*L1e[di];
      }
      P[t2]=s;
    }
    __syncthreads();
    const float inv_nq = 1.f/fmaxf(sqrtf(nq2), 1e-12f);
    const float a1h=a1[h];
    float lg[16], mx=-1e30f;
#pragma unroll
    for (int d=0; d<16; d++){
      float S=0.f;
#pragma unroll
      for (int t2=0;t2<9;t2++) S += P[t2]*we_lds[h*16+d][t2];
      const float l = S*inv_nq/fmaxf(nk_lds[b][h*16+d],1e-12f)*a1h;
      lg[d]=l; mx=fmaxf(mx,l);
    }
    float sum=0.f;
#pragma unroll
    for (int d=0;d<16;d++){ lg[d]=expf(lg[d]-mx); sum+=lg[d]; }
    const float inv=1.f/sum;
#pragma unroll
    for (int d=0;d<16;d++) attn_lds[b][h][c][d]=lg[d]*inv;
    __syncthreads();
    for (int i=tid;i<512;i+=256){
      const int G=i&127, o=(i>>7)&1, bb=i>>8;
      const int hh=G>>4, dd=G&15;
      float s=0.f;
#pragma unroll
      for (int cc=0;cc<16;cc++) s += w_proj[o*128 + hh*16+cc]*attn_lds[bb][hh][cc][dd];
      M_lds[bb][o][G]=s;
    }
    __syncthreads();
    if (tid<36){
      const int t=tid%9, o=(tid/9)&1, bb=tid/18;
      float sa=0.f, sb=0.f;
      for (int G=0;G<128;G++){
        const float m=M_lds[bb][o][G];
        const float wd=w_dw[(128+G)*9+t];
        sa += m*wd*w_conv1[(128+G)*2+0];
        sb += m*wd*w_conv1[(128+G)*2+1];
      }
      AB_lds[bb][o][0][t] = sa;
      AB_lds[bb][o][1][t] = sb;
    }
    __syncthreads();
  }

  // ----------------------------- Phase C: out ------------------------------
#pragma unroll
  for (int it=0; it<2; ++it){
    const int idx = it*65536 + blk*256 + tid;   // 131072 quad-pixels
    const int b  = idx >> 16;
    const int y  = (idx >> 7) & (IMG-1);
    const int xc = (idx & 127) << 2;
    const float* x0 = x + (size_t)b*2*NPIX;
    const float* x1 = x0 + NPIX;

    float A0[9],A1[9],B0[9],B1[9];
#pragma unroll
    for (int t=0;t<9;t++){
      A0[t]=AB_lds[b][0][0][t];  A1[t]=AB_lds[b][1][0][t];
      B0[t]=AB_lds[b][0][1][t];  B1[t]=AB_lds[b][1][1][t];
    }
    float v0[3][6], v1[3][6];
#pragma unroll
    for (int r=0;r<3;r++){
      const int yy=y-1+r;
      if ((unsigned)yy < (unsigned)IMG){
        const float* p0=x0+(size_t)yy*IMG;
        const float* p1=x1+(size_t)yy*IMG;
        const float4 m0=*(const float4*)(p0+xc);
        const float4 m1=*(const float4*)(p1+xc);
        v0[r][1]=m0.x; v0[r][2]=m0.y; v0[r][3]=m0.z; v0[r][4]=m0.w;
        v1[r][1]=m1.x; v1[r][2]=m1.y; v1[r][3]=m1.z; v1[r][4]=m1.w;
        v0[r][0]=(xc>0)?p0[xc-1]:0.f;        v1[r][0]=(xc>0)?p1[xc-1]:0.f;
        v0[r][5]=(xc+4<IMG)?p0[xc+4]:0.f;    v1[r][5]=(xc+4<IMG)?p1[xc+4]:0.f;
      } else {
#pragma unroll
        for (int c2=0;c2<6;c2++){v0[r][c2]=0.f;v1[r][c2]=0.f;}
      }
    }
    float res0[4], res1[4];
#pragma unroll
    for (int i=0;i<4;i++){
      float s0=v0[1][i+1];
      float s1=v1[1][i+1];
#pragma unroll
      for (int t=0;t<9;t++){
        const int ty=t/3, tx=t%3;
        const float g0=v0[ty][i+tx], g1=v1[ty][i+tx];
        s0 += A0[t]*g0 + B0[t]*g1;
        s1 += A1[t]*g0 + B1[t]*g1;
      }
      res0[i]=s0; res1[i]=s1;
    }
    float* o0p = out + ((size_t)(b*2+0)*IMG + y)*IMG + xc;
    float* o1p = out + ((size_t)(b*2+1)*IMG + y)*IMG + xc;
    *(float4*)o0p = make_float4(res0[0],res0[1],res0[2],res0[3]);
    *(float4*)o1p = make_float4(res1[0],res1[1],res1[2],res1[3]);
  }
}

extern "C" void kernel_launch(void* const* d_in, const int* in_sizes, int n_in,
                              void* d_out, int out_size, void* d_ws, size_t ws_size,
                              hipStream_t stream){
  const float* x       = (const float*)d_in[0];
  const float* e       = (const float*)d_in[1];
  const float* w_conv1 = (const float*)d_in[2];
  const float* w_dw    = (const float*)d_in[3];
  const float* w_ehead = (const float*)d_in[4];
  const float* w_proj  = (const float*)d_in[5];
  const float* a1      = (const float*)d_in[6];
  float* ws   = (float*)d_ws;
  float* part = ws;                              // 30*640 = 19200 floats
  unsigned int* bar = (unsigned int*)(ws + 19200);  // 32 counters, 64B apart
  float* out  = (float*)d_out;

  hipMemsetAsync(bar, 0, 32*16*sizeof(unsigned int), stream);
  hipLaunchKernelGGL(fused_kernel, dim3(NBLK), dim3(256), 0, stream,
                     x, e, w_conv1, w_dw, w_ehead, w_proj, a1, part, bar, out);
}